// Round 1
// baseline (829.455 us; speedup 1.0000x reference)
//
#include <hip/hip_runtime.h>

#define T_STEPS 512
#define HDIM    18
#define CHUNK   8
#define NTH     (CHUNK * HDIM)   /* 144 threads */
#define ROWP    20               /* padded LDS row length (80 B, 16B-aligned) */

__device__ __forceinline__ float fast_sig(float x) {
    return __builtin_amdgcn_rcpf(1.0f + __expf(-x));
}
__device__ __forceinline__ float fast_tanh(float x) {
    return 2.0f * __builtin_amdgcn_rcpf(1.0f + __expf(-2.0f * x)) - 1.0f;
}

__global__ __launch_bounds__(NTH, 2) void lstm2_kernel(
    const float* __restrict__ x,
    const float* __restrict__ wih0, const float* __restrict__ whh0,
    const float* __restrict__ bih0, const float* __restrict__ bhh0,
    const float* __restrict__ wih1, const float* __restrict__ whh1,
    const float* __restrict__ bih1, const float* __restrict__ bhh1,
    float* __restrict__ out)
{
    __shared__ __align__(16) float s_wih0[4 * HDIM][ROWP];
    __shared__ __align__(16) float s_wih1[4 * HDIM][ROWP];
    __shared__ __align__(16) float xbuf[2][CHUNK][ROWP];
    __shared__ __align__(16) float h1s[2][CHUNK][ROWP];
    __shared__ __align__(16) float h2s[2][CHUNK][ROWP];

    const int tid = threadIdx.x;
    const int bl  = tid / HDIM;        // local batch 0..7
    const int h   = tid % HDIM;        // hidden unit 0..17
    const int b   = blockIdx.x * CHUNK + bl;

    // ---- stage input-projection weights into LDS (padded rows) ----
    for (int i = tid; i < 4 * HDIM * HDIM; i += NTH) {
        const int r = i / HDIM, k = i % HDIM;
        s_wih0[r][k] = wih0[i];
        s_wih1[r][k] = wih1[i];
    }

    // ---- per-lane recurrent weights + fused biases in registers ----
    float whh0r[4][HDIM], whh1r[4][HDIM];
    float bz0[4], bz1[4];
    #pragma unroll
    for (int g = 0; g < 4; ++g) {
        const int r = g * HDIM + h;
        #pragma unroll
        for (int k = 0; k < HDIM; ++k) {
            whh0r[g][k] = whh0[r * HDIM + k];
            whh1r[g][k] = whh1[r * HDIM + k];
        }
        bz0[g] = bih0[r] + bhh0[r];
        bz1[g] = bih1[r] + bhh1[r];
    }

    // ---- init state ----
    h1s[0][bl][h] = 0.0f;
    h2s[0][bl][h] = 0.0f;
    float c1 = 0.0f, c2 = 0.0f;

    const float* xp = x + ((size_t)b * T_STEPS) * HDIM + h;  // this lane's x element stream
    float*       op = out + ((size_t)b * T_STEPS) * HDIM + h;
    xbuf[0][bl][h] = xp[0];

    __syncthreads();

    int p = 0;
    for (int t = 0; t < T_STEPS; ++t) {
        // prefetch next timestep's x element into a register (hidden under phase 1)
        float xnext = 0.0f;
        if (t + 1 < T_STEPS) xnext = xp[(size_t)(t + 1) * HDIM];

        // ================= layer 1 =================
        float a0 = bz0[0], a1 = bz0[1], a2 = bz0[2], a3 = bz0[3];
        {
            const float* xin = &xbuf[t & 1][bl][0];
            const float* w0  = &s_wih0[h][0];
            const float* w1  = &s_wih0[HDIM + h][0];
            const float* w2  = &s_wih0[2 * HDIM + h][0];
            const float* w3  = &s_wih0[3 * HDIM + h][0];
            #pragma unroll
            for (int k = 0; k < HDIM; ++k) {
                const float v = xin[k];
                a0 += w0[k] * v; a1 += w1[k] * v; a2 += w2[k] * v; a3 += w3[k] * v;
            }
            const float* hin = &h1s[p][bl][0];
            #pragma unroll
            for (int k = 0; k < HDIM; ++k) {
                const float v = hin[k];
                a0 += whh0r[0][k] * v; a1 += whh0r[1][k] * v;
                a2 += whh0r[2][k] * v; a3 += whh0r[3][k] * v;
            }
        }
        {
            const float ig = fast_sig(a0);
            const float fg = fast_sig(a1);
            const float gg = fast_tanh(a2);
            const float og = fast_sig(a3);
            c1 = fg * c1 + ig * gg;
            h1s[1 - p][bl][h] = og * fast_tanh(c1);
        }
        __syncthreads();   // h1[t] visible

        // ================= layer 2 =================
        a0 = bz1[0]; a1 = bz1[1]; a2 = bz1[2]; a3 = bz1[3];
        {
            const float* hin1 = &h1s[1 - p][bl][0];
            const float* w0   = &s_wih1[h][0];
            const float* w1   = &s_wih1[HDIM + h][0];
            const float* w2   = &s_wih1[2 * HDIM + h][0];
            const float* w3   = &s_wih1[3 * HDIM + h][0];
            #pragma unroll
            for (int k = 0; k < HDIM; ++k) {
                const float v = hin1[k];
                a0 += w0[k] * v; a1 += w1[k] * v; a2 += w2[k] * v; a3 += w3[k] * v;
            }
            const float* hin2 = &h2s[p][bl][0];
            #pragma unroll
            for (int k = 0; k < HDIM; ++k) {
                const float v = hin2[k];
                a0 += whh1r[0][k] * v; a1 += whh1r[1][k] * v;
                a2 += whh1r[2][k] * v; a3 += whh1r[3][k] * v;
            }
        }
        {
            const float ig = fast_sig(a0);
            const float fg = fast_sig(a1);
            const float gg = fast_tanh(a2);
            const float og = fast_sig(a3);
            c2 = fg * c2 + ig * gg;
            const float h2n = og * fast_tanh(c2);
            h2s[1 - p][bl][h] = h2n;
            op[(size_t)t * HDIM] = h2n;        // final output (layer-2 h)
        }
        xbuf[(t + 1) & 1][bl][h] = xnext;      // stage next x tile
        __syncthreads();   // h2[t], xbuf[t+1] visible
        p ^= 1;
    }
}

extern "C" void kernel_launch(void* const* d_in, const int* in_sizes, int n_in,
                              void* d_out, int out_size, void* d_ws, size_t ws_size,
                              hipStream_t stream) {
    const float* x    = (const float*)d_in[0];
    const float* wih0 = (const float*)d_in[1];
    const float* whh0 = (const float*)d_in[2];
    const float* bih0 = (const float*)d_in[3];
    const float* bhh0 = (const float*)d_in[4];
    const float* wih1 = (const float*)d_in[5];
    const float* whh1 = (const float*)d_in[6];
    const float* bih1 = (const float*)d_in[7];
    const float* bhh1 = (const float*)d_in[8];
    float* out = (float*)d_out;

    lstm2_kernel<<<dim3(4096 / CHUNK), dim3(NTH), 0, stream>>>(
        x, wih0, whh0, bih0, bhh0, wih1, whh1, bih1, bhh1, out);
}